// Round 4
// baseline (215.713 us; speedup 1.0000x reference)
//
#include <hip/hip_runtime.h>
#include <math.h>

// SecondOrderChannelAttension on MI355X (gfx950)
// B=32, C=64, H=W=96 -> M=9216, RED=8
//
// Pipeline (3 dispatches):
//   K1 gram_k:  GEMM-style staged Gram. Global reads are m-contiguous
//               (512B+ segments), fp32->bf16 convert, LDS tile in a
//               granule-permuted XOR-swizzled layout so MFMA fragment reads
//               are dense ds_read_b128. Each wave owns a 16-row block ->
//               no cross-wave reduce. Channel sums folded into staging.
//   K2 ns_k:    reduce partials, cov = Gram/M - mu mu^T, Newton-Schulz
//               (12 matmuls in LDS, all iterates symmetric), gate MLP.
//   K3 gate_mul: out = x * gate, nontemporal stores.

#define BB 32
#define CC 64
#define MM 9216

#define MT 128                  // m per LDS tile
#define NCHUNK 24               // blocks per batch
#define TPB 3                   // tiles per block: 24*3*128 = 9216

typedef __attribute__((ext_vector_type(8))) short bf16x8;
typedef __attribute__((ext_vector_type(4))) float f32x4;

__device__ __forceinline__ short f2bf(float f) {
  unsigned u = __builtin_bit_cast(unsigned, f);
  return (short)(unsigned short)((u + 0x8000u) >> 16);
}
__device__ __forceinline__ float bf2f(short h) {
  unsigned u = ((unsigned)(unsigned short)h) << 16;
  return __builtin_bit_cast(float, u);
}
// truncating pack of two floats into two bf16 lanes of one dword
__device__ __forceinline__ unsigned pack2(float lo, float hi) {
  unsigned ul = __builtin_bit_cast(unsigned, lo);
  unsigned uh = __builtin_bit_cast(unsigned, hi);
  return (uh & 0xffff0000u) | (ul >> 16);
}

// LDS granule position for (ch, g): granule = 8 consecutive m of one channel
// (16B bf16). Layout keyed for dense frag reads + bank-balanced writes.
__device__ __forceinline__ int gpos(int ch, int g) {
  return ((ch >> 4) * 4 + (g >> 2)) * 64 + (g & 3) * 16 + ((ch & 15) ^ g);
}

// ---------------- K1: staged partial Gram + channel sums ----------------
__global__ __launch_bounds__(256, 3) void gram_k(const float* __restrict__ x,
                                                 float* __restrict__ covpart,
                                                 float* __restrict__ sumpart) {
  __shared__ __align__(16) char smem[32768];  // 2 x 16KB bf16 tile buffers
  short* bufs[2] = {(short*)smem, (short*)(smem + 16384)};

  int b = blockIdx.x / NCHUNK;
  int chunk = blockIdx.x % NCHUNK;
  int tid = threadIdx.x;
  int w = tid >> 6, lane = tid & 63;
  int quad = lane >> 4, col = lane & 15;
  const float* xb = x + (size_t)b * CC * MM;
  int mchunk = chunk * (MT * TPB);

  f32x4 acc[4];
#pragma unroll
  for (int j = 0; j < 4; j++) acc[j] = (f32x4){0.f, 0.f, 0.f, 0.f};
  float csum[8];
#pragma unroll
  for (int i = 0; i < 8; i++) csum[i] = 0.f;

  // thread t covers float4 indices F = t + 256*i, i=0..7, within a tile:
  // ch = F>>5 (= (t>>5)+8i), f4 = F&31 -> m-contiguous lanes (512B segments)
  int ch0 = tid >> 5;          // 0..7
  int f4c = tid & 31;          // float4 column within row

  float4 pre[8];
#pragma unroll
  for (int i = 0; i < 8; i++)
    pre[i] = *(const float4*)(xb + (size_t)(ch0 + 8 * i) * MM + mchunk + f4c * 4);

  // convert + write tile 0 into buf 0
  {
    int g = f4c >> 1, h = f4c & 1;
#pragma unroll
    for (int i = 0; i < 8; i++) {
      float4 v = pre[i];
      csum[i] += ((v.x + v.y) + (v.z + v.w));
      uint2 d;
      d.x = pack2(v.x, v.y);
      d.y = pack2(v.z, v.w);
      *(uint2*)((char*)bufs[0] + gpos(ch0 + 8 * i, g) * 16 + h * 8) = d;
    }
  }
  __syncthreads();

  for (int tl = 0; tl < TPB; ++tl) {
    float4 nxt[8];
    if (tl + 1 < TPB) {
      int m0 = mchunk + (tl + 1) * MT;
#pragma unroll
      for (int i = 0; i < 8; i++)
        nxt[i] = *(const float4*)(xb + (size_t)(ch0 + 8 * i) * MM + m0 + f4c * 4);
    }
    // MFMA over current buffer
    const short* buf = bufs[tl & 1];
#pragma unroll
    for (int ks = 0; ks < 4; ks++) {
      int g = (ks << 2) | quad;
      bf16x8 fr[4];
#pragma unroll
      for (int j = 0; j < 4; j++)
        fr[j] = *(const bf16x8*)((const char*)buf +
                                 ((j * 4 + ks) * 64 + quad * 16 + (col ^ g)) * 16);
#pragma unroll
      for (int j = 0; j < 4; j++)
        acc[j] = __builtin_amdgcn_mfma_f32_16x16x32_bf16(fr[w], fr[j], acc[j], 0, 0, 0);
    }
    if (tl + 1 < TPB) {
      short* nb = bufs[(tl + 1) & 1];
      int g = f4c >> 1, h = f4c & 1;
#pragma unroll
      for (int i = 0; i < 8; i++) {
        float4 v = nxt[i];
        csum[i] += ((v.x + v.y) + (v.z + v.w));
        uint2 d;
        d.x = pack2(v.x, v.y);
        d.y = pack2(v.z, v.w);
        *(uint2*)((char*)nb + gpos(ch0 + 8 * i, g) * 16 + h * 8) = d;
      }
    }
    __syncthreads();
  }

  // partial Gram write: wave w owns rows 16w..16w+15, all 64 cols
  float* cp = covpart + (size_t)(b * NCHUNK + chunk) * 4096;
#pragma unroll
  for (int j = 0; j < 4; j++)
#pragma unroll
    for (int r = 0; r < 4; r++)
      __builtin_nontemporal_store(acc[j][r],
          cp + (w * 16 + quad * 4 + r) * 64 + j * 16 + col);

  // channel sums: csum[i] belongs to ch = ch0 + 8i; reduce 32 threads/ch in LDS
  float* csl = (float*)smem;  // reuse tile buffers (64 x 32 fp32 = 8KB)
#pragma unroll
  for (int i = 0; i < 8; i++) csl[(ch0 + 8 * i) * 32 + (tid & 31)] = csum[i];
  __syncthreads();
  if (tid < 64) {
    float s = 0.f;
#pragma unroll
    for (int k = 0; k < 32; k++) s += csl[tid * 32 + k];
    sumpart[(size_t)(b * NCHUNK + chunk) * 64 + tid] = s;
  }
}

// ---------------- K2: reduce + Newton-Schulz + gate MLP ----------------
__device__ __forceinline__ void mm64(short* __restrict__ D, const short* __restrict__ A,
                                     const short* __restrict__ Bm, int tid) {
  int w = tid >> 6, lane = tid & 63, quad = lane >> 4, col = lane & 15;
  f32x4 acc[4];
#pragma unroll
  for (int j = 0; j < 4; j++) acc[j] = (f32x4){0.f, 0.f, 0.f, 0.f};
#pragma unroll
  for (int ks = 0; ks < 2; ks++) {
    int k0 = ks * 32 + quad * 8;
    bf16x8 fa = *(const bf16x8*)(A + (w * 16 + col) * 64 + k0);
#pragma unroll
    for (int j = 0; j < 4; j++) {
      bf16x8 fb = *(const bf16x8*)(Bm + (j * 16 + col) * 64 + k0);
      acc[j] = __builtin_amdgcn_mfma_f32_16x16x32_bf16(fa, fb, acc[j], 0, 0, 0);
    }
  }
#pragma unroll
  for (int j = 0; j < 4; j++)
#pragma unroll
    for (int r = 0; r < 4; r++)
      D[(w * 16 + quad * 4 + r) * 64 + j * 16 + col] = f2bf(acc[j][r]);
}

__device__ __forceinline__ void mmcolsum(const short* __restrict__ A,
                                         const short* __restrict__ Bm,
                                         float* scol, int tid) {
  int w = tid >> 6, lane = tid & 63, quad = lane >> 4, col = lane & 15;
  f32x4 acc[4];
#pragma unroll
  for (int j = 0; j < 4; j++) acc[j] = (f32x4){0.f, 0.f, 0.f, 0.f};
#pragma unroll
  for (int ks = 0; ks < 2; ks++) {
    int k0 = ks * 32 + quad * 8;
    bf16x8 fa = *(const bf16x8*)(A + (w * 16 + col) * 64 + k0);
#pragma unroll
    for (int j = 0; j < 4; j++) {
      bf16x8 fb = *(const bf16x8*)(Bm + (j * 16 + col) * 64 + k0);
      acc[j] = __builtin_amdgcn_mfma_f32_16x16x32_bf16(fa, fb, acc[j], 0, 0, 0);
    }
  }
#pragma unroll
  for (int j = 0; j < 4; j++) {
    float t = (acc[j][0] + acc[j][1]) + (acc[j][2] + acc[j][3]);
    atomicAdd(&scol[j * 16 + col], t);
  }
}

__global__ __launch_bounds__(256) void ns_k(const float* __restrict__ covpart,
                                            const float* __restrict__ sumpart,
                                            const float* __restrict__ w1,
                                            const float* __restrict__ pb1,
                                            const float* __restrict__ w2,
                                            const float* __restrict__ pb2,
                                            float* __restrict__ gatews) {
  __shared__ __align__(16) short nb0[4096], nb1[4096], nb2[4096], nb3[4096], nb4[4096];
  __shared__ __align__(16) float gbuf[4096];
  __shared__ float mu[64];
  __shared__ float scol[64];
  __shared__ float hbuf[8];
  __shared__ float normA_sh;
  int b = blockIdx.x;
  int tid = threadIdx.x;

  const float4* cp = (const float4*)covpart + (size_t)b * NCHUNK * 1024;
  float4* gb4 = (float4*)gbuf;
#pragma unroll
  for (int e = 0; e < 4; e++) {
    int idx = tid + 256 * e;
    float4 s = {0.f, 0.f, 0.f, 0.f};
    for (int ch = 0; ch < NCHUNK; ch++) {
      float4 v = cp[(size_t)ch * 1024 + idx];
      s.x += v.x; s.y += v.y; s.z += v.z; s.w += v.w;
    }
    gb4[idx] = s;
  }
  if (tid < 64) {
    float s = 0.f;
    for (int ch = 0; ch < NCHUNK; ch++) s += sumpart[(size_t)(b * NCHUNK + ch) * 64 + tid];
    mu[tid] = s * (1.0f / MM);
  }
  __syncthreads();
  if (tid < 64) {
    float d = gbuf[tid * 65] * (1.0f / MM) - mu[tid] * mu[tid];
#pragma unroll
    for (int off = 32; off >= 1; off >>= 1) d += __shfl_down(d, off);
    if (tid == 0) normA_sh = d;
  }
  __syncthreads();
  float rn = 1.0f / normA_sh;
#pragma unroll
  for (int e = 0; e < 16; e++) {
    int idx = tid + 256 * e;
    int r = idx >> 6, c = idx & 63;
    float cv = gbuf[idx] * (1.0f / MM) - mu[r] * mu[c];
    float a = cv * rn;
    nb0[idx] = f2bf(a);
    nb1[idx] = f2bf((r == c ? 1.5f : 0.0f) - 0.5f * a);
  }
  __syncthreads();
  mm64(nb2, nb0, nb1, tid);  // Y = A @ ZY0
  __syncthreads();
  short *pY = nb2, *pZ = nb1, *s0 = nb3, *s1 = nb4, *s2 = nb0;
  for (int it = 0; it < 3; ++it) {
#pragma unroll
    for (int e = 0; e < 16; e++) {  // T = 1.5I - 0.5 Z
      int idx = tid + 256 * e;
      int r = idx >> 6, c = idx & 63;
      float z = bf2f(pZ[idx]);
      s0[idx] = f2bf((r == c ? 1.5f : 0.0f) - 0.5f * z);
    }
    __syncthreads();
    mm64(s1, s0, pY, tid);  // W = T @ Y
    __syncthreads();
    mm64(s2, pY, s1, tid);  // Ynew = Y @ W
    mm64(s0, s1, pZ, tid);  // Znew = W @ Z
    __syncthreads();
    short* oY = pY; short* oZ = pZ; short* oW = s1;
    pY = s2; pZ = s0; s0 = oY; s1 = oZ; s2 = oW;
  }
  mm64(s0, pZ, pY, tid);  // P = Z @ Y
  __syncthreads();
#pragma unroll
  for (int e = 0; e < 16; e++) {  // s0 = 3I - P
    int idx = tid + 256 * e;
    int r = idx >> 6, c = idx & 63;
    float p = bf2f(s0[idx]);
    s0[idx] = f2bf((r == c ? 3.0f : 0.0f) - p);
  }
  if (tid < 64) scol[tid] = 0.0f;
  __syncthreads();
  mmcolsum(pY, s0, scol, tid);  // column sums of R = Y @ (3I - P)
  __syncthreads();
  if (tid < 8) {
    float sc = 0.5f * sqrtf(normA_sh) * (1.0f / 64.0f);
    float acc = pb1[tid];
    for (int c = 0; c < 64; c++) acc += scol[c] * sc * w1[tid * 64 + c];
    hbuf[tid] = fmaxf(acc, 0.0f);
  }
  __syncthreads();
  if (tid < 64) {
    float acc = pb2[tid];
#pragma unroll
    for (int j = 0; j < 8; j++) acc += hbuf[j] * w2[tid * 8 + j];
    gatews[b * 64 + tid] = 1.0f / (1.0f + __expf(-acc));
  }
}

// ---------------- K3: out = x * gate ----------------
#define N4 (BB * CC * MM / 4)  // 4718592 float4; 2304 float4 per (b,c)
__global__ __launch_bounds__(256) void gate_mul(const float* __restrict__ x,
                                                const float* __restrict__ gatews,
                                                float* __restrict__ out) {
  int i = blockIdx.x * 256 + threadIdx.x;
  int bc = i / 2304;
  float g = gatews[bc];
  f32x4 v = *(const f32x4*)((const float*)x + (size_t)i * 4);
  v *= g;
  __builtin_nontemporal_store(v, (f32x4*)((float*)out + (size_t)i * 4));
}

extern "C" void kernel_launch(void* const* d_in, const int* in_sizes, int n_in,
                              void* d_out, int out_size, void* d_ws, size_t ws_size,
                              hipStream_t stream) {
  const float* x = (const float*)d_in[0];
  const float* w1 = (const float*)d_in[1];
  const float* b1 = (const float*)d_in[2];
  const float* w2 = (const float*)d_in[3];
  const float* b2 = (const float*)d_in[4];
  float* out = (float*)d_out;
  float* ws = (float*)d_ws;
  float* covpart = ws;                                   // 32*24*4096 fp32 (12.6 MB)
  float* sumpart = covpart + (size_t)BB * NCHUNK * 4096; // 32*24*64 fp32
  float* gatews = sumpart + (size_t)BB * NCHUNK * 64;    // 32*64 fp32

  gram_k<<<BB * NCHUNK, 256, 0, stream>>>(x, covpart, sumpart);
  ns_k<<<BB, 256, 0, stream>>>(covpart, sumpart, w1, b1, w2, b2, gatews);
  gate_mul<<<N4 / 256, 256, 0, stream>>>(x, gatews, out);
}

// Round 5
// 178.264 us; speedup vs baseline: 1.2101x; 1.2101x over previous
//
#include <hip/hip_runtime.h>
#include <math.h>

// SecondOrderChannelAttension on MI355X (gfx950)
// B=32, C=64, H=W=96 -> M=9216, RED=8
//
// Pipeline (3 dispatches):
//   K1 gram_k:  GEMM-style staged Gram. Global reads are m-contiguous
//               (512B segments), fp32->bf16 convert, LDS tile in a
//               granule-permuted XOR-swizzled layout so MFMA fragment reads
//               are dense ds_read_b128. Each wave owns a 16-row block ->
//               no cross-wave reduce. Channel sums folded into staging.
//               NOTE: A-fragment is read from LDS with a w-dependent ADDRESS;
//               never index a register array by wave id (scratch demotion!).
//   K2 ns_k:    reduce partials, cov = Gram/M - mu mu^T, Newton-Schulz
//               (12 matmuls in LDS, all iterates symmetric), gate MLP.
//   K3 gate_mul: out = x * gate, nontemporal stores.

#define BB 32
#define CC 64
#define MM 9216

#define MT 128                  // m per LDS tile
#define NCHUNK 24               // blocks per batch
#define TPB 3                   // tiles per block: 24*3*128 = 9216

typedef __attribute__((ext_vector_type(8))) short bf16x8;
typedef __attribute__((ext_vector_type(4))) float f32x4;

__device__ __forceinline__ short f2bf(float f) {
  unsigned u = __builtin_bit_cast(unsigned, f);
  return (short)(unsigned short)((u + 0x8000u) >> 16);
}
__device__ __forceinline__ float bf2f(short h) {
  unsigned u = ((unsigned)(unsigned short)h) << 16;
  return __builtin_bit_cast(float, u);
}
// truncating pack of two floats into two bf16 lanes of one dword
__device__ __forceinline__ unsigned pack2(float lo, float hi) {
  unsigned ul = __builtin_bit_cast(unsigned, lo);
  unsigned uh = __builtin_bit_cast(unsigned, hi);
  return (uh & 0xffff0000u) | (ul >> 16);
}

// LDS granule position for (ch, g): granule = 8 consecutive m of one channel
// (16B bf16). Layout keyed for dense frag reads + bank-balanced writes.
__device__ __forceinline__ int gpos(int ch, int g) {
  return ((ch >> 4) * 4 + (g >> 2)) * 64 + (g & 3) * 16 + ((ch & 15) ^ g);
}

// ---------------- K1: staged partial Gram + channel sums ----------------
__global__ __launch_bounds__(256, 3) void gram_k(const float* __restrict__ x,
                                                 float* __restrict__ covpart,
                                                 float* __restrict__ sumpart) {
  __shared__ __align__(16) char smem[32768];  // 2 x 16KB bf16 tile buffers

  int b = blockIdx.x / NCHUNK;
  int chunk = blockIdx.x % NCHUNK;
  int tid = threadIdx.x;
  int w = tid >> 6, lane = tid & 63;
  int quad = lane >> 4, col = lane & 15;
  const float* xb = x + (size_t)b * CC * MM;
  int mchunk = chunk * (MT * TPB);

  f32x4 acc[4];
#pragma unroll
  for (int j = 0; j < 4; j++) acc[j] = (f32x4){0.f, 0.f, 0.f, 0.f};
  float csum[8];
#pragma unroll
  for (int i = 0; i < 8; i++) csum[i] = 0.f;

  // thread t covers float4 indices F = t + 256*i, i=0..7, within a tile:
  // ch = F>>5 (= (t>>5)+8i), f4 = F&31 -> m-contiguous lanes (512B segments)
  int ch0 = tid >> 5;          // 0..7
  int f4c = tid & 31;          // float4 column within row

  float4 pre[8];
#pragma unroll
  for (int i = 0; i < 8; i++)
    pre[i] = *(const float4*)(xb + (size_t)(ch0 + 8 * i) * MM + mchunk + f4c * 4);

  // convert + write tile 0 into buf 0
  {
    int g = f4c >> 1, h = f4c & 1;
#pragma unroll
    for (int i = 0; i < 8; i++) {
      float4 v = pre[i];
      csum[i] += ((v.x + v.y) + (v.z + v.w));
      uint2 d;
      d.x = pack2(v.x, v.y);
      d.y = pack2(v.z, v.w);
      *(uint2*)(smem + gpos(ch0 + 8 * i, g) * 16 + h * 8) = d;
    }
  }
  __syncthreads();

#pragma unroll
  for (int tl = 0; tl < TPB; ++tl) {
    float4 nxt[8];
    if (tl + 1 < TPB) {
      int m0 = mchunk + (tl + 1) * MT;
#pragma unroll
      for (int i = 0; i < 8; i++)
        nxt[i] = *(const float4*)(xb + (size_t)(ch0 + 8 * i) * MM + m0 + f4c * 4);
    }
    // MFMA over current buffer; A-frag address (not register index) uses w
    const char* buf = smem + (tl & 1) * 16384;
#pragma unroll
    for (int ks = 0; ks < 4; ks++) {
      int g = (ks << 2) | quad;
      int co = quad * 16 + (col ^ g);
      bf16x8 fa = *(const bf16x8*)(buf + ((w * 4 + ks) * 64 + co) * 16);
#pragma unroll
      for (int j = 0; j < 4; j++) {
        bf16x8 fb = *(const bf16x8*)(buf + ((j * 4 + ks) * 64 + co) * 16);
        acc[j] = __builtin_amdgcn_mfma_f32_16x16x32_bf16(fa, fb, acc[j], 0, 0, 0);
      }
    }
    if (tl + 1 < TPB) {
      char* nb = smem + ((tl + 1) & 1) * 16384;
      int g = f4c >> 1, h = f4c & 1;
#pragma unroll
      for (int i = 0; i < 8; i++) {
        float4 v = nxt[i];
        csum[i] += ((v.x + v.y) + (v.z + v.w));
        uint2 d;
        d.x = pack2(v.x, v.y);
        d.y = pack2(v.z, v.w);
        *(uint2*)(nb + gpos(ch0 + 8 * i, g) * 16 + h * 8) = d;
      }
    }
    __syncthreads();
  }

  // partial Gram write: wave w owns rows 16w..16w+15, all 64 cols
  float* cp = covpart + (size_t)(b * NCHUNK + chunk) * 4096;
#pragma unroll
  for (int j = 0; j < 4; j++)
#pragma unroll
    for (int r = 0; r < 4; r++)
      __builtin_nontemporal_store(acc[j][r],
          cp + (w * 16 + quad * 4 + r) * 64 + j * 16 + col);

  // channel sums: csum[i] belongs to ch = ch0 + 8i; reduce 32 threads/ch in LDS
  float* csl = (float*)smem;  // reuse tile buffers (64 x 32 fp32 = 8KB)
#pragma unroll
  for (int i = 0; i < 8; i++) csl[(ch0 + 8 * i) * 32 + (tid & 31)] = csum[i];
  __syncthreads();
  if (tid < 64) {
    float s = 0.f;
#pragma unroll
    for (int k = 0; k < 32; k++) s += csl[tid * 32 + k];
    sumpart[(size_t)(b * NCHUNK + chunk) * 64 + tid] = s;
  }
}

// ---------------- K2: reduce + Newton-Schulz + gate MLP ----------------
__device__ __forceinline__ void mm64(short* __restrict__ D, const short* __restrict__ A,
                                     const short* __restrict__ Bm, int tid) {
  int w = tid >> 6, lane = tid & 63, quad = lane >> 4, col = lane & 15;
  f32x4 acc[4];
#pragma unroll
  for (int j = 0; j < 4; j++) acc[j] = (f32x4){0.f, 0.f, 0.f, 0.f};
#pragma unroll
  for (int ks = 0; ks < 2; ks++) {
    int k0 = ks * 32 + quad * 8;
    bf16x8 fa = *(const bf16x8*)(A + (w * 16 + col) * 64 + k0);
#pragma unroll
    for (int j = 0; j < 4; j++) {
      bf16x8 fb = *(const bf16x8*)(Bm + (j * 16 + col) * 64 + k0);
      acc[j] = __builtin_amdgcn_mfma_f32_16x16x32_bf16(fa, fb, acc[j], 0, 0, 0);
    }
  }
#pragma unroll
  for (int j = 0; j < 4; j++)
#pragma unroll
    for (int r = 0; r < 4; r++)
      D[(w * 16 + quad * 4 + r) * 64 + j * 16 + col] = f2bf(acc[j][r]);
}

__device__ __forceinline__ void mmcolsum(const short* __restrict__ A,
                                         const short* __restrict__ Bm,
                                         float* scol, int tid) {
  int w = tid >> 6, lane = tid & 63, quad = lane >> 4, col = lane & 15;
  f32x4 acc[4];
#pragma unroll
  for (int j = 0; j < 4; j++) acc[j] = (f32x4){0.f, 0.f, 0.f, 0.f};
#pragma unroll
  for (int ks = 0; ks < 2; ks++) {
    int k0 = ks * 32 + quad * 8;
    bf16x8 fa = *(const bf16x8*)(A + (w * 16 + col) * 64 + k0);
#pragma unroll
    for (int j = 0; j < 4; j++) {
      bf16x8 fb = *(const bf16x8*)(Bm + (j * 16 + col) * 64 + k0);
      acc[j] = __builtin_amdgcn_mfma_f32_16x16x32_bf16(fa, fb, acc[j], 0, 0, 0);
    }
  }
#pragma unroll
  for (int j = 0; j < 4; j++) {
    float t = (acc[j][0] + acc[j][1]) + (acc[j][2] + acc[j][3]);
    atomicAdd(&scol[j * 16 + col], t);
  }
}

__global__ __launch_bounds__(256) void ns_k(const float* __restrict__ covpart,
                                            const float* __restrict__ sumpart,
                                            const float* __restrict__ w1,
                                            const float* __restrict__ pb1,
                                            const float* __restrict__ w2,
                                            const float* __restrict__ pb2,
                                            float* __restrict__ gatews) {
  __shared__ __align__(16) short nb0[4096], nb1[4096], nb2[4096], nb3[4096], nb4[4096];
  __shared__ __align__(16) float gbuf[4096];
  __shared__ float mu[64];
  __shared__ float scol[64];
  __shared__ float hbuf[8];
  __shared__ float normA_sh;
  int b = blockIdx.x;
  int tid = threadIdx.x;

  const float4* cp = (const float4*)covpart + (size_t)b * NCHUNK * 1024;
  float4* gb4 = (float4*)gbuf;
#pragma unroll
  for (int e = 0; e < 4; e++) {
    int idx = tid + 256 * e;
    float4 s = {0.f, 0.f, 0.f, 0.f};
    for (int ch = 0; ch < NCHUNK; ch++) {
      float4 v = cp[(size_t)ch * 1024 + idx];
      s.x += v.x; s.y += v.y; s.z += v.z; s.w += v.w;
    }
    gb4[idx] = s;
  }
  if (tid < 64) {
    float s = 0.f;
    for (int ch = 0; ch < NCHUNK; ch++) s += sumpart[(size_t)(b * NCHUNK + ch) * 64 + tid];
    mu[tid] = s * (1.0f / MM);
  }
  __syncthreads();
  if (tid < 64) {
    float d = gbuf[tid * 65] * (1.0f / MM) - mu[tid] * mu[tid];
#pragma unroll
    for (int off = 32; off >= 1; off >>= 1) d += __shfl_down(d, off);
    if (tid == 0) normA_sh = d;
  }
  __syncthreads();
  float rn = 1.0f / normA_sh;
#pragma unroll
  for (int e = 0; e < 16; e++) {
    int idx = tid + 256 * e;
    int r = idx >> 6, c = idx & 63;
    float cv = gbuf[idx] * (1.0f / MM) - mu[r] * mu[c];
    float a = cv * rn;
    nb0[idx] = f2bf(a);
    nb1[idx] = f2bf((r == c ? 1.5f : 0.0f) - 0.5f * a);
  }
  __syncthreads();
  mm64(nb2, nb0, nb1, tid);  // Y = A @ ZY0
  __syncthreads();
  short *pY = nb2, *pZ = nb1, *s0 = nb3, *s1 = nb4, *s2 = nb0;
  for (int it = 0; it < 3; ++it) {
#pragma unroll
    for (int e = 0; e < 16; e++) {  // T = 1.5I - 0.5 Z
      int idx = tid + 256 * e;
      int r = idx >> 6, c = idx & 63;
      float z = bf2f(pZ[idx]);
      s0[idx] = f2bf((r == c ? 1.5f : 0.0f) - 0.5f * z);
    }
    __syncthreads();
    mm64(s1, s0, pY, tid);  // W = T @ Y
    __syncthreads();
    mm64(s2, pY, s1, tid);  // Ynew = Y @ W
    mm64(s0, s1, pZ, tid);  // Znew = W @ Z
    __syncthreads();
    short* oY = pY; short* oZ = pZ; short* oW = s1;
    pY = s2; pZ = s0; s0 = oY; s1 = oZ; s2 = oW;
  }
  mm64(s0, pZ, pY, tid);  // P = Z @ Y
  __syncthreads();
#pragma unroll
  for (int e = 0; e < 16; e++) {  // s0 = 3I - P
    int idx = tid + 256 * e;
    int r = idx >> 6, c = idx & 63;
    float p = bf2f(s0[idx]);
    s0[idx] = f2bf((r == c ? 3.0f : 0.0f) - p);
  }
  if (tid < 64) scol[tid] = 0.0f;
  __syncthreads();
  mmcolsum(pY, s0, scol, tid);  // column sums of R = Y @ (3I - P)
  __syncthreads();
  if (tid < 8) {
    float sc = 0.5f * sqrtf(normA_sh) * (1.0f / 64.0f);
    float acc = pb1[tid];
    for (int c = 0; c < 64; c++) acc += scol[c] * sc * w1[tid * 64 + c];
    hbuf[tid] = fmaxf(acc, 0.0f);
  }
  __syncthreads();
  if (tid < 64) {
    float acc = pb2[tid];
#pragma unroll
    for (int j = 0; j < 8; j++) acc += hbuf[j] * w2[tid * 8 + j];
    gatews[b * 64 + tid] = 1.0f / (1.0f + __expf(-acc));
  }
}

// ---------------- K3: out = x * gate ----------------
#define N4 (BB * CC * MM / 4)  // 4718592 float4; 2304 float4 per (b,c)
__global__ __launch_bounds__(256) void gate_mul(const float* __restrict__ x,
                                                const float* __restrict__ gatews,
                                                float* __restrict__ out) {
  int i = blockIdx.x * 256 + threadIdx.x;
  int bc = i / 2304;
  float g = gatews[bc];
  f32x4 v = *(const f32x4*)((const float*)x + (size_t)i * 4);
  v *= g;
  __builtin_nontemporal_store(v, (f32x4*)((float*)out + (size_t)i * 4));
}

extern "C" void kernel_launch(void* const* d_in, const int* in_sizes, int n_in,
                              void* d_out, int out_size, void* d_ws, size_t ws_size,
                              hipStream_t stream) {
  const float* x = (const float*)d_in[0];
  const float* w1 = (const float*)d_in[1];
  const float* b1 = (const float*)d_in[2];
  const float* w2 = (const float*)d_in[3];
  const float* b2 = (const float*)d_in[4];
  float* out = (float*)d_out;
  float* ws = (float*)d_ws;
  float* covpart = ws;                                   // 32*24*4096 fp32 (12.6 MB)
  float* sumpart = covpart + (size_t)BB * NCHUNK * 4096; // 32*24*64 fp32
  float* gatews = sumpart + (size_t)BB * NCHUNK * 64;    // 32*64 fp32

  gram_k<<<BB * NCHUNK, 256, 0, stream>>>(x, covpart, sumpart);
  ns_k<<<BB, 256, 0, stream>>>(covpart, sumpart, w1, b1, w2, b2, gatews);
  gate_mul<<<N4 / 256, 256, 0, stream>>>(x, gatews, out);
}